// Round 9
// baseline (133.112 us; speedup 1.0000x reference)
//
#include <hip/hip_runtime.h>
#include <math.h>

// Problem constants (fixed by the reference).
constexpr int kN  = 250000;
constexpr int kC  = 32;
constexpr int kFC = 16;
constexpr int kFN = 16;
constexpr int kV  = 64;
constexpr int kBlock = 1024;

// Half-table row stride in dwords: 16 classes + 2 pad (72B rows).
// Measured r8: 5.9M conflict-cycles over 32M b128 reads = 0.18 cyc/inst -> ok.
constexpr int kRowDw = 18;

// ws layout (dwords unless noted):
//   [0..1023]     {A=-0.5/s^2, B=m/s^2} interleaved per (c,f)
//   [1024..1055]  K_c (incl. folded C and log-prior)
//   [1056]        reject count (int, zeroed by prep each launch)
//   [1088..33855] ltab[r=(f,v)][c] = logf(cat_probs[c][r])  (128 KiB)
//   [kOffB ..]    best  [2][kN] f32
//   [+2kN]        second[2][kN] f32
//   [+4kN]        besti [2][kN] u8   (2kN bytes)
//   [..]          reject list [kN] i32
constexpr int kOffCnt  = 1056;
constexpr int kOffTab  = 1088;
constexpr int kOffB    = kOffTab + 1024 * kC;      // 33856
constexpr int kOffS    = kOffB + 2 * kN;
constexpr int kOffIBdw = kOffB + 4 * kN;           // besti, u8, 2kN bytes
constexpr int kOffList = kOffIBdw + (2 * kN + 3) / 4;
constexpr size_t kWsNeedSplit = (size_t)(kOffList + kN) * 4;   // ~5.64 MB

// ---------------------------------------------------------------------------
// Round-8 forensics: structure resolved (merge ~5us, exact off the top-5,
// fill=45us harness-fixed). nbc_half = 44us, VALU-bound (46.8% busy), and
// the largest VALU term is staging: 16 logf/thread x 490 blocks = 8M logf
// recomputing a launch-invariant 128KB table.
// Round-9: prep precomputes ltab (transpose-log, 33k logf once); half's
// staging becomes pure copy (4x float4 L2 load + 4x ds_write_b128).
// Table values bit-identical (same logf, same inputs) -> accept logic,
// thresholds, merge, exact ALL unchanged (8x-validated, absmax 0).
//
// Numerics: per-class T_c op order identical to round 5; top2(32) = exact
// merge of two top2(16), half-0 preferred on ties. Accept iff T_best >=
// -86 AND gap >= 8e-3 (approx bound B<=2e-3, gap >= 4B). Rejects: full
// exact reference sequence, one class per lane, 5-step shfl_xor argmax
// (max-value / min-index-tie = jnp.argmax first-max semantics).
// ---------------------------------------------------------------------------

__global__ __launch_bounds__(256) void nbc_prep(
    const float* __restrict__ class_probs,
    const float* __restrict__ means,
    const float* __restrict__ stds,
    const float* __restrict__ cat_probs,
    float* __restrict__ ws,
    int use_tab)
{
    const int b = blockIdx.x;
    const int t = threadIdx.x;
    if (b == 0) {
        const float two_pi = 2.0f * (float)M_PI;
        for (int i = t; i < kC * kFN; i += 256) {
            float m  = means[i];
            float s  = stds[i];
            float rs = 1.0f / s;
            ws[2 * i]     = -0.5f * rs * rs;        // A
            ws[2 * i + 1] = m * rs * rs;            // B
        }
        if (t == 0) reinterpret_cast<int*>(ws)[kOffCnt] = 0;   // reject count
        if (t < kC) {
            float k = logf(class_probs[t]);
            for (int f = 0; f < kFN; ++f) {
                float s  = stds[t * kFN + f];
                float m  = means[t * kFN + f];
                float rs = 1.0f / s;
                k += logf(1.0f / (two_pi * (s * s)));
                k += -0.5f * (m * rs) * (m * rs);   // C folded into K
            }
            ws[1024 + t] = k;
        }
    } else if (use_tab) {
        // blocks 1..32: transpose-log 1024 source elements each.
        // s = c*1024 + r (source-linear, coalesced reads) -> ltab[r*32 + c].
        const int base = (b - 1) * 1024;
        for (int k2 = 0; k2 < 4; ++k2) {
            int s = base + t + k2 * 256;
            int c = s >> 10;
            int r = s & 1023;
            ws[kOffTab + r * 32 + c] = logf(cat_probs[s]);
        }
    }
}

// ---- split path: one block = (sample-chunk, class-half) ----
__global__ __launch_bounds__(kBlock) void nbc_half(
    const int*   __restrict__ X_cat,
    const float* __restrict__ X_num,
    const float* __restrict__ cat_probs,
    float* __restrict__ ws)
{
    __shared__ float lcat[1024 * kRowDw];   // [r=(f,v)][class-in-half], 72 KiB

    const int chunk = blockIdx.x >> 1;
    const int half  = blockIdx.x & 1;
    const int tid   = threadIdx.x;
    const int n     = chunk * kBlock + tid;
    const bool active = (n < kN);

    unsigned pack[4];
    float    x[kFN];
    if (active) {
        const int4* p4 = reinterpret_cast<const int4*>(X_cat + (size_t)n * kFC);
        int4 a0 = p4[0], a1 = p4[1], a2 = p4[2], a3 = p4[3];
        pack[0] = (unsigned)a0.x | ((unsigned)a0.y << 8) |
                  ((unsigned)a0.z << 16) | ((unsigned)a0.w << 24);
        pack[1] = (unsigned)a1.x | ((unsigned)a1.y << 8) |
                  ((unsigned)a1.z << 16) | ((unsigned)a1.w << 24);
        pack[2] = (unsigned)a2.x | ((unsigned)a2.y << 8) |
                  ((unsigned)a2.z << 16) | ((unsigned)a2.w << 24);
        pack[3] = (unsigned)a3.x | ((unsigned)a3.y << 8) |
                  ((unsigned)a3.z << 16) | ((unsigned)a3.w << 24);

        const float4* q4 = reinterpret_cast<const float4*>(X_num + (size_t)n * kFN);
        float4 b0 = q4[0], b1 = q4[1], b2 = q4[2], b3 = q4[3];
        x[0]=b0.x;  x[1]=b0.y;  x[2]=b0.z;  x[3]=b0.w;
        x[4]=b1.x;  x[5]=b1.y;  x[6]=b1.z;  x[7]=b1.w;
        x[8]=b2.x;  x[9]=b2.y;  x[10]=b2.z; x[11]=b2.w;
        x[12]=b3.x; x[13]=b3.y; x[14]=b3.z; x[15]=b3.w;
    } else {
        pack[0] = pack[1] = pack[2] = pack[3] = 0u;
        #pragma unroll
        for (int f = 0; f < kFN; ++f) x[f] = 0.0f;
    }

    // stage this half's log-table: PURE COPY from precomputed ltab.
    // thread t = row r; 4x (L2-resident float4 load + ds_write_b128).
    {
        #pragma unroll
        for (int q = 0; q < 4; ++q) {
            float4 w = *reinterpret_cast<const float4*>(
                ws + kOffTab + tid * 32 + (half << 4) + q * 4);
            *reinterpret_cast<float4*>(lcat + tid * kRowDw + q * 4) = w;
        }
    }
    __syncthreads();

    if (!active) return;

    int rowdw[kFC];
    #pragma unroll
    for (int f = 0; f < kFC; ++f) {
        const int v = (pack[f >> 2] >> ((f & 3) * 8)) & 63;
        rowdw[f] = ((f << 6) + v) * kRowDw;
    }

    const float2* __restrict__ P = reinterpret_cast<const float2*>(ws); // {A,B}
    const float*  __restrict__ K = ws + 1024;

    float best = -INFINITY, second = -INFINITY;
    int   besti = 0;

    #pragma unroll 1
    for (int grp = 0; grp < 4; ++grp) {
        const int cbase = (half << 4) + (grp << 2);   // global class base
        float acc[4];

        #pragma unroll
        for (int j = 0; j < 4; ++j) {
            const int c = cbase + j;                  // wave-uniform
            float a = K[c];
            #pragma unroll
            for (int f = 0; f < kFN; ++f) {
                float2 p = P[(c << 4) + f];
                a = fmaf(x[f], fmaf(x[f], p.x, p.y), a);
            }
            acc[j] = a;
        }

        #pragma unroll
        for (int f = 0; f < kFC; ++f) {
            const float4 t = *reinterpret_cast<const float4*>(
                &lcat[rowdw[f] + (grp << 2)]);
            acc[0] += t.x;
            acc[1] += t.y;
            acc[2] += t.z;
            acc[3] += t.w;
        }

        #pragma unroll
        for (int j = 0; j < 4; ++j) {
            float T = acc[j];
            if (T > best)        { second = best; best = T; besti = cbase + j; }
            else if (T > second) { second = T; }
        }
    }

    // coalesced SoA result write (besti as u8)
    ws[kOffB + half * kN + n] = best;
    ws[kOffS + half * kN + n] = second;
    reinterpret_cast<unsigned char*>(ws)[(size_t)kOffIBdw * 4 + half * kN + n] =
        (unsigned char)besti;
}

// ---- streaming merge: accept -> out; reject -> compact list ----
__global__ __launch_bounds__(256) void nbc_merge_fast(
    float* __restrict__ ws,
    int* __restrict__ out)
{
    const int n = blockIdx.x * 256 + threadIdx.x;
    if (n >= kN) return;

    const float b0 = ws[kOffB + n];
    const float b1 = ws[kOffB + kN + n];
    const float s0 = ws[kOffS + n];
    const float s1 = ws[kOffS + kN + n];
    const unsigned char* ib =
        reinterpret_cast<const unsigned char*>(ws) + (size_t)kOffIBdw * 4;
    const int i0 = ib[n];
    const int i1 = ib[kN + n];

    // exact top-2 merge; ties -> half 0 (lower class index = ref first-max)
    float wb, ws2; int wi;
    if (b1 > b0) { wb = b1; wi = i1; ws2 = fmaxf(b0, s1); }
    else         { wb = b0; wi = i0; ws2 = fmaxf(b1, s0); }

    if (wb >= -86.0f && (wb - ws2) >= 8.0e-3f) {
        out[n] = wi;
    } else {
        int slot = atomicAdd(reinterpret_cast<int*>(ws) + kOffCnt, 1);
        reinterpret_cast<int*>(ws)[kOffList + slot] = n;
    }
}

// ---- dense exact scoring of the reject list: ONE CLASS PER LANE ----
__global__ __launch_bounds__(256) void nbc_exact(
    const int*   __restrict__ X_cat,
    const float* __restrict__ X_num,
    const float* __restrict__ class_probs,
    const float* __restrict__ cat_probs,
    const float* __restrict__ means,
    const float* __restrict__ stds,
    const float* __restrict__ ws,
    int* __restrict__ out)
{
    const int total  = reinterpret_cast<const int*>(ws)[kOffCnt];
    const int c      = threadIdx.x & 31;                 // this lane's class
    const int gid0   = (blockIdx.x * 256 + threadIdx.x) >> 5;
    const int gstride = (gridDim.x * 256) >> 5;
    const float two_pi = 2.0f * (float)M_PI;

    for (int g = gid0; g < total; g += gstride) {
        const int n = reinterpret_cast<const int*>(ws)[kOffList + g];

        unsigned pack[4];
        float    x[kFN];
        {
            const int4* p4 = reinterpret_cast<const int4*>(X_cat + (size_t)n * kFC);
            int4 a0 = p4[0], a1 = p4[1], a2 = p4[2], a3 = p4[3];
            pack[0] = (unsigned)a0.x | ((unsigned)a0.y << 8) |
                      ((unsigned)a0.z << 16) | ((unsigned)a0.w << 24);
            pack[1] = (unsigned)a1.x | ((unsigned)a1.y << 8) |
                      ((unsigned)a1.z << 16) | ((unsigned)a1.w << 24);
            pack[2] = (unsigned)a2.x | ((unsigned)a2.y << 8) |
                      ((unsigned)a2.z << 16) | ((unsigned)a2.w << 24);
            pack[3] = (unsigned)a3.x | ((unsigned)a3.y << 8) |
                      ((unsigned)a3.z << 16) | ((unsigned)a3.w << 24);

            const float4* q4 =
                reinterpret_cast<const float4*>(X_num + (size_t)n * kFN);
            float4 c0 = q4[0], c1 = q4[1], c2 = q4[2], c3 = q4[3];
            x[0]=c0.x;  x[1]=c0.y;  x[2]=c0.z;  x[3]=c0.w;
            x[4]=c1.x;  x[5]=c1.y;  x[6]=c1.z;  x[7]=c1.w;
            x[8]=c2.x;  x[9]=c2.y;  x[10]=c2.z; x[11]=c2.w;
            x[12]=c3.x; x[13]=c3.y; x[14]=c3.z; x[15]=c3.w;
        }

        // Exact reference sequence for THIS lane's class (validated op order).
        const float* __restrict__ row = cat_probs + (size_t)c * (kFC * kV);
        float cat = row[pack[0] & 63];
        #pragma unroll
        for (int f = 1; f < kFC; ++f) {
            const int v = (pack[f >> 2] >> ((f & 3) * 8)) & 63;
            cat *= row[(f << 6) + v];
        }
        float num;
        #pragma unroll
        for (int f = 0; f < kFN; ++f) {
            float m = means[c * kFN + f];
            float s = stds [c * kFN + f];
            float inv = 1.0f / (two_pi * (s * s));
            float z = (x[f] - m) / s;              // IEEE divide
            float e = expf(-0.5f * (z * z));
            float lik = inv * e;
            num = (f == 0) ? lik : num * lik;
        }
        float pred = (class_probs[c] * cat) * num; // ((cp*cat)*num) like ref

        // 32-lane argmax reduce: max value, min class index on ties.
        float bb = pred;
        int   bi = c;
        #pragma unroll
        for (int m2 = 1; m2 < 32; m2 <<= 1) {
            float ov = __shfl_xor(bb, m2);
            int   oi = __shfl_xor(bi, m2);
            if (ov > bb || (ov == bb && oi < bi)) { bb = ov; bi = oi; }
        }
        if (c == 0) out[n] = bi;                   // first-max semantics
    }
}

// ---- mono fallback (round-5 kernel, proven): used only if ws too small ----
__global__ __launch_bounds__(kBlock) void nbc_mono(
    const int*   __restrict__ X_cat,
    const float* __restrict__ X_num,
    const float* __restrict__ class_probs,
    const float* __restrict__ cat_probs,
    const float* __restrict__ means,
    const float* __restrict__ stds,
    const float* __restrict__ ws,
    int* __restrict__ out)
{
    __shared__ float lcat[1024 * 36];

    const int tid = threadIdx.x;
    const int n   = blockIdx.x * kBlock + tid;
    const bool active = (n < kN);

    unsigned pack[4];
    float    x[kFN];
    if (active) {
        const int4* p4 = reinterpret_cast<const int4*>(X_cat + (size_t)n * kFC);
        int4 a0 = p4[0], a1 = p4[1], a2 = p4[2], a3 = p4[3];
        pack[0] = (unsigned)a0.x | ((unsigned)a0.y << 8) |
                  ((unsigned)a0.z << 16) | ((unsigned)a0.w << 24);
        pack[1] = (unsigned)a1.x | ((unsigned)a1.y << 8) |
                  ((unsigned)a1.z << 16) | ((unsigned)a1.w << 24);
        pack[2] = (unsigned)a2.x | ((unsigned)a2.y << 8) |
                  ((unsigned)a2.z << 16) | ((unsigned)a2.w << 24);
        pack[3] = (unsigned)a3.x | ((unsigned)a3.y << 8) |
                  ((unsigned)a3.z << 16) | ((unsigned)a3.w << 24);
        const float4* q4 = reinterpret_cast<const float4*>(X_num + (size_t)n * kFN);
        float4 b0 = q4[0], b1 = q4[1], b2 = q4[2], b3 = q4[3];
        x[0]=b0.x;  x[1]=b0.y;  x[2]=b0.z;  x[3]=b0.w;
        x[4]=b1.x;  x[5]=b1.y;  x[6]=b1.z;  x[7]=b1.w;
        x[8]=b2.x;  x[9]=b2.y;  x[10]=b2.z; x[11]=b2.w;
        x[12]=b3.x; x[13]=b3.y; x[14]=b3.z; x[15]=b3.w;
    } else {
        pack[0] = pack[1] = pack[2] = pack[3] = 0u;
        #pragma unroll
        for (int f = 0; f < kFN; ++f) x[f] = 0.0f;
    }

    #pragma unroll
    for (int cg = 0; cg < 8; ++cg) {
        float4 w;
        w.x = logf(cat_probs[(size_t)(cg * 4 + 0) * 1024 + tid]);
        w.y = logf(cat_probs[(size_t)(cg * 4 + 1) * 1024 + tid]);
        w.z = logf(cat_probs[(size_t)(cg * 4 + 2) * 1024 + tid]);
        w.w = logf(cat_probs[(size_t)(cg * 4 + 3) * 1024 + tid]);
        *reinterpret_cast<float4*>(lcat + (size_t)tid * 36 + cg * 4) = w;
    }
    __syncthreads();

    if (!active) return;

    int rowdw[kFC];
    #pragma unroll
    for (int f = 0; f < kFC; ++f) {
        const int v = (pack[f >> 2] >> ((f & 3) * 8)) & 63;
        rowdw[f] = ((f << 6) + v) * 36;
    }

    const float2* __restrict__ P = reinterpret_cast<const float2*>(ws);
    const float*  __restrict__ K = ws + 1024;

    float best = -INFINITY, second = -INFINITY;
    int   besti = 0;

    #pragma unroll 1
    for (int grp = 0; grp < 8; ++grp) {
        const int cbase = grp << 2;
        float acc[4];
        #pragma unroll
        for (int j = 0; j < 4; ++j) {
            const int c = cbase + j;
            float a = K[c];
            #pragma unroll
            for (int f = 0; f < kFN; ++f) {
                float2 p = P[(c << 4) + f];
                a = fmaf(x[f], fmaf(x[f], p.x, p.y), a);
            }
            acc[j] = a;
        }
        #pragma unroll
        for (int f = 0; f < kFC; ++f) {
            const float4 t = *reinterpret_cast<const float4*>(
                &lcat[rowdw[f] + (grp << 2)]);
            acc[0] += t.x; acc[1] += t.y; acc[2] += t.z; acc[3] += t.w;
        }
        #pragma unroll
        for (int j = 0; j < 4; ++j) {
            float T = acc[j];
            if (T > best)        { second = best; best = T; besti = cbase + j; }
            else if (T > second) { second = T; }
        }
    }

    if (best >= -86.0f && (best - second) >= 8.0e-3f) {
        out[n] = besti;
        return;
    }

    const float thr    = (best >= -86.0f) ? (best - 1.6e-2f) : -INFINITY;
    const float two_pi = 2.0f * (float)M_PI;
    float bb = -INFINITY;
    int   bi = 0;
    for (int c = 0; c < kC; ++c) {
        float a = K[c];
        #pragma unroll
        for (int f = 0; f < kFN; ++f) {
            float2 p = P[(c << 4) + f];
            a = fmaf(x[f], fmaf(x[f], p.x, p.y), a);
        }
        #pragma unroll
        for (int f = 0; f < kFC; ++f) a += lcat[rowdw[f] + c];

        if (a >= thr) {
            const float* __restrict__ row = cat_probs + (size_t)c * (kFC * kV);
            float cat = row[pack[0] & 63];
            #pragma unroll
            for (int f = 1; f < kFC; ++f) {
                const int v = (pack[f >> 2] >> ((f & 3) * 8)) & 63;
                cat *= row[(f << 6) + v];
            }
            float num;
            #pragma unroll
            for (int f = 0; f < kFN; ++f) {
                float m = means[c * kFN + f];
                float s = stds [c * kFN + f];
                float inv = 1.0f / (two_pi * (s * s));
                float z = (x[f] - m) / s;
                float e = expf(-0.5f * (z * z));
                float lik = inv * e;
                num = (f == 0) ? lik : num * lik;
            }
            float pred = (class_probs[c] * cat) * num;
            if (pred > bb) { bb = pred; bi = c; }
        }
    }
    out[n] = bi;
}

extern "C" void kernel_launch(void* const* d_in, const int* in_sizes, int n_in,
                              void* d_out, int out_size, void* d_ws, size_t ws_size,
                              hipStream_t stream) {
    const int*   X_cat       = (const int*)  d_in[0];
    const float* X_num       = (const float*)d_in[1];
    const float* class_probs = (const float*)d_in[2];
    const float* cat_probs   = (const float*)d_in[3];
    const float* means       = (const float*)d_in[4];
    const float* stds        = (const float*)d_in[5];
    int*   out = (int*)d_out;
    float* ws  = (float*)d_ws;

    const int use_tab = (ws_size >= kWsNeedSplit) ? 1 : 0;

    hipLaunchKernelGGL(nbc_prep, dim3(use_tab ? 33 : 1), dim3(256), 0, stream,
                       class_probs, means, stds, cat_probs, ws, use_tab);

    const int chunks = (kN + kBlock - 1) / kBlock;          // 245
    if (use_tab) {
        hipLaunchKernelGGL(nbc_half, dim3(chunks * 2), dim3(kBlock), 0, stream,
                           X_cat, X_num, cat_probs, ws);
        hipLaunchKernelGGL(nbc_merge_fast, dim3((kN + 255) / 256), dim3(256),
                           0, stream, ws, out);
        hipLaunchKernelGGL(nbc_exact, dim3(2048), dim3(256), 0, stream,
                           X_cat, X_num, class_probs, cat_probs, means, stds,
                           ws, out);
    } else {
        hipLaunchKernelGGL(nbc_mono, dim3(chunks), dim3(kBlock), 0, stream,
                           X_cat, X_num, class_probs, cat_probs, means, stds,
                           ws, out);
    }
}

// Round 10
// 131.121 us; speedup vs baseline: 1.0152x; 1.0152x over previous
//
#include <hip/hip_runtime.h>
#include <math.h>

// Problem constants (fixed by the reference).
constexpr int kN  = 250000;
constexpr int kC  = 32;
constexpr int kFC = 16;
constexpr int kFN = 16;
constexpr int kV  = 64;
constexpr int kBlock = 1024;

// Half-table row stride: 16 classes + 2 pad floats = 72B = 9 float2.
// Round-9 forensics: b128 reads on this stride = +11.8 cyc/inst conflicts
// (8-mod-16 row alignment + even-only start banks). b64 (float2) accesses
// are 8B-aligned by construction and spread 64 lanes x 2 banks over 16
// even start positions = ~4 accesses/bank = near the 4-cycle floor.
constexpr int kRowF2 = 9;

// ws layout (dwords unless noted):
//   [0..1023]     {A=-0.5/s^2, B=m/s^2} interleaved per (c,f)
//   [1024..1055]  K_c (incl. folded C and log-prior)
//   [1056]        reject count (int, zeroed by prep each launch)
//   [1088..33855] ltab[r=(f,v)][c] = logf(cat_probs[c][r])  (128 KiB)
//   [kOffB ..]    best  [2][kN] f32
//   [+2kN]        second[2][kN] f32
//   [+4kN]        besti [2][kN] u8   (2kN bytes)
//   [..]          reject list [kN] i32
constexpr int kOffCnt  = 1056;
constexpr int kOffTab  = 1088;
constexpr int kOffB    = kOffTab + 1024 * kC;      // 33856
constexpr int kOffS    = kOffB + 2 * kN;
constexpr int kOffIBdw = kOffB + 4 * kN;           // besti, u8, 2kN bytes
constexpr int kOffList = kOffIBdw + (2 * kN + 3) / 4;
constexpr size_t kWsNeedSplit = (size_t)(kOffList + kN) * 4;   // ~5.64 MB

// ---------------------------------------------------------------------------
// Numerics (9x-validated, unchanged): per-class T_c op order identical to
// round 5; top2(32) = exact merge of two top2(16), half-0 preferred on
// ties. Accept iff T_best >= -86 AND gap >= 8e-3 (approx bound B<=2e-3,
// gap >= 4B). Rejects: full exact reference sequence, one class per lane,
// 5-step shfl_xor argmax (max-value / min-index-tie = first-max).
// ---------------------------------------------------------------------------

__global__ __launch_bounds__(256) void nbc_prep(
    const float* __restrict__ class_probs,
    const float* __restrict__ means,
    const float* __restrict__ stds,
    const float* __restrict__ cat_probs,
    float* __restrict__ ws,
    int use_tab)
{
    const int b = blockIdx.x;
    const int t = threadIdx.x;
    if (b == 0) {
        const float two_pi = 2.0f * (float)M_PI;
        for (int i = t; i < kC * kFN; i += 256) {
            float m  = means[i];
            float s  = stds[i];
            float rs = 1.0f / s;
            ws[2 * i]     = -0.5f * rs * rs;        // A
            ws[2 * i + 1] = m * rs * rs;            // B
        }
        if (t == 0) reinterpret_cast<int*>(ws)[kOffCnt] = 0;   // reject count
        if (t < kC) {
            float k = logf(class_probs[t]);
            for (int f = 0; f < kFN; ++f) {
                float s  = stds[t * kFN + f];
                float m  = means[t * kFN + f];
                float rs = 1.0f / s;
                k += logf(1.0f / (two_pi * (s * s)));
                k += -0.5f * (m * rs) * (m * rs);   // C folded into K
            }
            ws[1024 + t] = k;
        }
    } else if (use_tab) {
        // blocks 1..32: transpose-log 1024 source elements each.
        // s = c*1024 + r (source-linear, coalesced reads) -> ltab[r*32 + c].
        const int base = (b - 1) * 1024;
        for (int k2 = 0; k2 < 4; ++k2) {
            int s = base + t + k2 * 256;
            int c = s >> 10;
            int r = s & 1023;
            ws[kOffTab + r * 32 + c] = logf(cat_probs[s]);
        }
    }
}

// ---- split path: one block = (sample-chunk, class-half) ----
__global__ __launch_bounds__(kBlock) void nbc_half(
    const int*   __restrict__ X_cat,
    const float* __restrict__ X_num,
    const float* __restrict__ cat_probs,
    float* __restrict__ ws)
{
    // [r=(f,v)][class-in-half] log-table, 1024 rows x 9 float2 = 72 KiB.
    __shared__ float2 lcat[1024 * kRowF2];

    const int chunk = blockIdx.x >> 1;
    const int half  = blockIdx.x & 1;
    const int tid   = threadIdx.x;
    const int n     = chunk * kBlock + tid;
    const bool active = (n < kN);

    unsigned pack[4];
    float    x[kFN];
    if (active) {
        const int4* p4 = reinterpret_cast<const int4*>(X_cat + (size_t)n * kFC);
        int4 a0 = p4[0], a1 = p4[1], a2 = p4[2], a3 = p4[3];
        pack[0] = (unsigned)a0.x | ((unsigned)a0.y << 8) |
                  ((unsigned)a0.z << 16) | ((unsigned)a0.w << 24);
        pack[1] = (unsigned)a1.x | ((unsigned)a1.y << 8) |
                  ((unsigned)a1.z << 16) | ((unsigned)a1.w << 24);
        pack[2] = (unsigned)a2.x | ((unsigned)a2.y << 8) |
                  ((unsigned)a2.z << 16) | ((unsigned)a2.w << 24);
        pack[3] = (unsigned)a3.x | ((unsigned)a3.y << 8) |
                  ((unsigned)a3.z << 16) | ((unsigned)a3.w << 24);

        const float4* q4 = reinterpret_cast<const float4*>(X_num + (size_t)n * kFN);
        float4 b0 = q4[0], b1 = q4[1], b2 = q4[2], b3 = q4[3];
        x[0]=b0.x;  x[1]=b0.y;  x[2]=b0.z;  x[3]=b0.w;
        x[4]=b1.x;  x[5]=b1.y;  x[6]=b1.z;  x[7]=b1.w;
        x[8]=b2.x;  x[9]=b2.y;  x[10]=b2.z; x[11]=b2.w;
        x[12]=b3.x; x[13]=b3.y; x[14]=b3.z; x[15]=b3.w;
    } else {
        pack[0] = pack[1] = pack[2] = pack[3] = 0u;
        #pragma unroll
        for (int f = 0; f < kFN; ++f) x[f] = 0.0f;
    }

    // stage this half's log-table: pure copy from precomputed ltab.
    // thread t = row r; 4x (L2-resident float4 load + 2x 8B LDS write).
    {
        #pragma unroll
        for (int q = 0; q < 4; ++q) {
            float4 w = *reinterpret_cast<const float4*>(
                ws + kOffTab + tid * 32 + (half << 4) + q * 4);
            lcat[tid * kRowF2 + q * 2]     = make_float2(w.x, w.y);
            lcat[tid * kRowF2 + q * 2 + 1] = make_float2(w.z, w.w);
        }
    }
    __syncthreads();

    if (!active) return;

    // Per-feature row base as float2 offset; group adds (grp<<1).
    int rowf2[kFC];
    #pragma unroll
    for (int f = 0; f < kFC; ++f) {
        const int v = (pack[f >> 2] >> ((f & 3) * 8)) & 63;
        rowf2[f] = ((f << 6) + v) * kRowF2;
    }

    const float2* __restrict__ P = reinterpret_cast<const float2*>(ws); // {A,B}
    const float*  __restrict__ K = ws + 1024;

    float best = -INFINITY, second = -INFINITY;
    int   besti = 0;

    #pragma unroll 1
    for (int grp = 0; grp < 4; ++grp) {
        const int cbase = (half << 4) + (grp << 2);   // global class base
        float acc[4];

        #pragma unroll
        for (int j = 0; j < 4; ++j) {
            const int c = cbase + j;                  // wave-uniform
            float a = K[c];
            #pragma unroll
            for (int f = 0; f < kFN; ++f) {
                float2 p = P[(c << 4) + f];
                a = fmaf(x[f], fmaf(x[f], p.x, p.y), a);
            }
            acc[j] = a;
        }

        // categorical log-adds: two 8B-aligned b64 reads per feature.
        #pragma unroll
        for (int f = 0; f < kFC; ++f) {
            const float2 lo = lcat[rowf2[f] + (grp << 1)];
            const float2 hi = lcat[rowf2[f] + (grp << 1) + 1];
            acc[0] += lo.x;
            acc[1] += lo.y;
            acc[2] += hi.x;
            acc[3] += hi.y;
        }

        #pragma unroll
        for (int j = 0; j < 4; ++j) {
            float T = acc[j];
            if (T > best)        { second = best; best = T; besti = cbase + j; }
            else if (T > second) { second = T; }
        }
    }

    // coalesced SoA result write (besti as u8)
    ws[kOffB + half * kN + n] = best;
    ws[kOffS + half * kN + n] = second;
    reinterpret_cast<unsigned char*>(ws)[(size_t)kOffIBdw * 4 + half * kN + n] =
        (unsigned char)besti;
}

// ---- streaming merge: accept -> out; reject -> compact list ----
__global__ __launch_bounds__(256) void nbc_merge_fast(
    float* __restrict__ ws,
    int* __restrict__ out)
{
    const int n = blockIdx.x * 256 + threadIdx.x;
    if (n >= kN) return;

    const float b0 = ws[kOffB + n];
    const float b1 = ws[kOffB + kN + n];
    const float s0 = ws[kOffS + n];
    const float s1 = ws[kOffS + kN + n];
    const unsigned char* ib =
        reinterpret_cast<const unsigned char*>(ws) + (size_t)kOffIBdw * 4;
    const int i0 = ib[n];
    const int i1 = ib[kN + n];

    // exact top-2 merge; ties -> half 0 (lower class index = ref first-max)
    float wb, ws2; int wi;
    if (b1 > b0) { wb = b1; wi = i1; ws2 = fmaxf(b0, s1); }
    else         { wb = b0; wi = i0; ws2 = fmaxf(b1, s0); }

    if (wb >= -86.0f && (wb - ws2) >= 8.0e-3f) {
        out[n] = wi;
    } else {
        int slot = atomicAdd(reinterpret_cast<int*>(ws) + kOffCnt, 1);
        reinterpret_cast<int*>(ws)[kOffList + slot] = n;
    }
}

// ---- dense exact scoring of the reject list: ONE CLASS PER LANE ----
__global__ __launch_bounds__(256) void nbc_exact(
    const int*   __restrict__ X_cat,
    const float* __restrict__ X_num,
    const float* __restrict__ class_probs,
    const float* __restrict__ cat_probs,
    const float* __restrict__ means,
    const float* __restrict__ stds,
    const float* __restrict__ ws,
    int* __restrict__ out)
{
    const int total  = reinterpret_cast<const int*>(ws)[kOffCnt];
    const int c      = threadIdx.x & 31;                 // this lane's class
    const int gid0   = (blockIdx.x * 256 + threadIdx.x) >> 5;
    const int gstride = (gridDim.x * 256) >> 5;
    const float two_pi = 2.0f * (float)M_PI;

    for (int g = gid0; g < total; g += gstride) {
        const int n = reinterpret_cast<const int*>(ws)[kOffList + g];

        unsigned pack[4];
        float    x[kFN];
        {
            const int4* p4 = reinterpret_cast<const int4*>(X_cat + (size_t)n * kFC);
            int4 a0 = p4[0], a1 = p4[1], a2 = p4[2], a3 = p4[3];
            pack[0] = (unsigned)a0.x | ((unsigned)a0.y << 8) |
                      ((unsigned)a0.z << 16) | ((unsigned)a0.w << 24);
            pack[1] = (unsigned)a1.x | ((unsigned)a1.y << 8) |
                      ((unsigned)a1.z << 16) | ((unsigned)a1.w << 24);
            pack[2] = (unsigned)a2.x | ((unsigned)a2.y << 8) |
                      ((unsigned)a2.z << 16) | ((unsigned)a2.w << 24);
            pack[3] = (unsigned)a3.x | ((unsigned)a3.y << 8) |
                      ((unsigned)a3.z << 16) | ((unsigned)a3.w << 24);

            const float4* q4 =
                reinterpret_cast<const float4*>(X_num + (size_t)n * kFN);
            float4 c0 = q4[0], c1 = q4[1], c2 = q4[2], c3 = q4[3];
            x[0]=c0.x;  x[1]=c0.y;  x[2]=c0.z;  x[3]=c0.w;
            x[4]=c1.x;  x[5]=c1.y;  x[6]=c1.z;  x[7]=c1.w;
            x[8]=c2.x;  x[9]=c2.y;  x[10]=c2.z; x[11]=c2.w;
            x[12]=c3.x; x[13]=c3.y; x[14]=c3.z; x[15]=c3.w;
        }

        // Exact reference sequence for THIS lane's class (validated op order).
        const float* __restrict__ row = cat_probs + (size_t)c * (kFC * kV);
        float cat = row[pack[0] & 63];
        #pragma unroll
        for (int f = 1; f < kFC; ++f) {
            const int v = (pack[f >> 2] >> ((f & 3) * 8)) & 63;
            cat *= row[(f << 6) + v];
        }
        float num;
        #pragma unroll
        for (int f = 0; f < kFN; ++f) {
            float m = means[c * kFN + f];
            float s = stds [c * kFN + f];
            float inv = 1.0f / (two_pi * (s * s));
            float z = (x[f] - m) / s;              // IEEE divide
            float e = expf(-0.5f * (z * z));
            float lik = inv * e;
            num = (f == 0) ? lik : num * lik;
        }
        float pred = (class_probs[c] * cat) * num; // ((cp*cat)*num) like ref

        // 32-lane argmax reduce: max value, min class index on ties.
        float bb = pred;
        int   bi = c;
        #pragma unroll
        for (int m2 = 1; m2 < 32; m2 <<= 1) {
            float ov = __shfl_xor(bb, m2);
            int   oi = __shfl_xor(bi, m2);
            if (ov > bb || (ov == bb && oi < bi)) { bb = ov; bi = oi; }
        }
        if (c == 0) out[n] = bi;                   // first-max semantics
    }
}

// ---- mono fallback (round-5 kernel, proven): used only if ws too small ----
__global__ __launch_bounds__(kBlock) void nbc_mono(
    const int*   __restrict__ X_cat,
    const float* __restrict__ X_num,
    const float* __restrict__ class_probs,
    const float* __restrict__ cat_probs,
    const float* __restrict__ means,
    const float* __restrict__ stds,
    const float* __restrict__ ws,
    int* __restrict__ out)
{
    __shared__ float lcat[1024 * 36];

    const int tid = threadIdx.x;
    const int n   = blockIdx.x * kBlock + tid;
    const bool active = (n < kN);

    unsigned pack[4];
    float    x[kFN];
    if (active) {
        const int4* p4 = reinterpret_cast<const int4*>(X_cat + (size_t)n * kFC);
        int4 a0 = p4[0], a1 = p4[1], a2 = p4[2], a3 = p4[3];
        pack[0] = (unsigned)a0.x | ((unsigned)a0.y << 8) |
                  ((unsigned)a0.z << 16) | ((unsigned)a0.w << 24);
        pack[1] = (unsigned)a1.x | ((unsigned)a1.y << 8) |
                  ((unsigned)a1.z << 16) | ((unsigned)a1.w << 24);
        pack[2] = (unsigned)a2.x | ((unsigned)a2.y << 8) |
                  ((unsigned)a2.z << 16) | ((unsigned)a2.w << 24);
        pack[3] = (unsigned)a3.x | ((unsigned)a3.y << 8) |
                  ((unsigned)a3.z << 16) | ((unsigned)a3.w << 24);
        const float4* q4 = reinterpret_cast<const float4*>(X_num + (size_t)n * kFN);
        float4 b0 = q4[0], b1 = q4[1], b2 = q4[2], b3 = q4[3];
        x[0]=b0.x;  x[1]=b0.y;  x[2]=b0.z;  x[3]=b0.w;
        x[4]=b1.x;  x[5]=b1.y;  x[6]=b1.z;  x[7]=b1.w;
        x[8]=b2.x;  x[9]=b2.y;  x[10]=b2.z; x[11]=b2.w;
        x[12]=b3.x; x[13]=b3.y; x[14]=b3.z; x[15]=b3.w;
    } else {
        pack[0] = pack[1] = pack[2] = pack[3] = 0u;
        #pragma unroll
        for (int f = 0; f < kFN; ++f) x[f] = 0.0f;
    }

    #pragma unroll
    for (int cg = 0; cg < 8; ++cg) {
        float4 w;
        w.x = logf(cat_probs[(size_t)(cg * 4 + 0) * 1024 + tid]);
        w.y = logf(cat_probs[(size_t)(cg * 4 + 1) * 1024 + tid]);
        w.z = logf(cat_probs[(size_t)(cg * 4 + 2) * 1024 + tid]);
        w.w = logf(cat_probs[(size_t)(cg * 4 + 3) * 1024 + tid]);
        *reinterpret_cast<float4*>(lcat + (size_t)tid * 36 + cg * 4) = w;
    }
    __syncthreads();

    if (!active) return;

    int rowdw[kFC];
    #pragma unroll
    for (int f = 0; f < kFC; ++f) {
        const int v = (pack[f >> 2] >> ((f & 3) * 8)) & 63;
        rowdw[f] = ((f << 6) + v) * 36;
    }

    const float2* __restrict__ P = reinterpret_cast<const float2*>(ws);
    const float*  __restrict__ K = ws + 1024;

    float best = -INFINITY, second = -INFINITY;
    int   besti = 0;

    #pragma unroll 1
    for (int grp = 0; grp < 8; ++grp) {
        const int cbase = grp << 2;
        float acc[4];
        #pragma unroll
        for (int j = 0; j < 4; ++j) {
            const int c = cbase + j;
            float a = K[c];
            #pragma unroll
            for (int f = 0; f < kFN; ++f) {
                float2 p = P[(c << 4) + f];
                a = fmaf(x[f], fmaf(x[f], p.x, p.y), a);
            }
            acc[j] = a;
        }
        #pragma unroll
        for (int f = 0; f < kFC; ++f) {
            const float4 t = *reinterpret_cast<const float4*>(
                &lcat[rowdw[f] + (grp << 2)]);
            acc[0] += t.x; acc[1] += t.y; acc[2] += t.z; acc[3] += t.w;
        }
        #pragma unroll
        for (int j = 0; j < 4; ++j) {
            float T = acc[j];
            if (T > best)        { second = best; best = T; besti = cbase + j; }
            else if (T > second) { second = T; }
        }
    }

    if (best >= -86.0f && (best - second) >= 8.0e-3f) {
        out[n] = besti;
        return;
    }

    const float thr    = (best >= -86.0f) ? (best - 1.6e-2f) : -INFINITY;
    const float two_pi = 2.0f * (float)M_PI;
    float bb = -INFINITY;
    int   bi = 0;
    for (int c = 0; c < kC; ++c) {
        float a = K[c];
        #pragma unroll
        for (int f = 0; f < kFN; ++f) {
            float2 p = P[(c << 4) + f];
            a = fmaf(x[f], fmaf(x[f], p.x, p.y), a);
        }
        #pragma unroll
        for (int f = 0; f < kFC; ++f) a += lcat[rowdw[f] + c];

        if (a >= thr) {
            const float* __restrict__ row = cat_probs + (size_t)c * (kFC * kV);
            float cat = row[pack[0] & 63];
            #pragma unroll
            for (int f = 1; f < kFC; ++f) {
                const int v = (pack[f >> 2] >> ((f & 3) * 8)) & 63;
                cat *= row[(f << 6) + v];
            }
            float num;
            #pragma unroll
            for (int f = 0; f < kFN; ++f) {
                float m = means[c * kFN + f];
                float s = stds [c * kFN + f];
                float inv = 1.0f / (two_pi * (s * s));
                float z = (x[f] - m) / s;
                float e = expf(-0.5f * (z * z));
                float lik = inv * e;
                num = (f == 0) ? lik : num * lik;
            }
            float pred = (class_probs[c] * cat) * num;
            if (pred > bb) { bb = pred; bi = c; }
        }
    }
    out[n] = bi;
}

extern "C" void kernel_launch(void* const* d_in, const int* in_sizes, int n_in,
                              void* d_out, int out_size, void* d_ws, size_t ws_size,
                              hipStream_t stream) {
    const int*   X_cat       = (const int*)  d_in[0];
    const float* X_num       = (const float*)d_in[1];
    const float* class_probs = (const float*)d_in[2];
    const float* cat_probs   = (const float*)d_in[3];
    const float* means       = (const float*)d_in[4];
    const float* stds        = (const float*)d_in[5];
    int*   out = (int*)d_out;
    float* ws  = (float*)d_ws;

    const int use_tab = (ws_size >= kWsNeedSplit) ? 1 : 0;

    hipLaunchKernelGGL(nbc_prep, dim3(use_tab ? 33 : 1), dim3(256), 0, stream,
                       class_probs, means, stds, cat_probs, ws, use_tab);

    const int chunks = (kN + kBlock - 1) / kBlock;          // 245
    if (use_tab) {
        hipLaunchKernelGGL(nbc_half, dim3(chunks * 2), dim3(kBlock), 0, stream,
                           X_cat, X_num, cat_probs, ws);
        hipLaunchKernelGGL(nbc_merge_fast, dim3((kN + 255) / 256), dim3(256),
                           0, stream, ws, out);
        hipLaunchKernelGGL(nbc_exact, dim3(2048), dim3(256), 0, stream,
                           X_cat, X_num, class_probs, cat_probs, means, stds,
                           ws, out);
    } else {
        hipLaunchKernelGGL(nbc_mono, dim3(chunks), dim3(kBlock), 0, stream,
                           X_cat, X_num, class_probs, cat_probs, means, stds,
                           ws, out);
    }
}